// Round 6
// baseline (231.711 us; speedup 1.0000x reference)
//
#include <hip/hip_runtime.h>
#include <cstdint>
#include <math.h>

// ---------------------------------------------------------------------------
// AttentionBlock: GroupNorm(32) -> 1x1 conv QKV -> MHA(8 heads, hd=64)
//                 -> 1x1 conv proj -> +residual.   B=16, C=512, N=H*W=1024.
// I/O tensors are FP32. Internal math: bf16 MFMA.
//
// Q/K/V are stored FRAGMENT-ORDERED per (b,h) so attention loads are fully
// coalesced single-burst reads:
//   qsw/ksw (A/B-frag of 16x16x32): per (blk=n>>4, ks=d>>5) 512-elem tile,
//       elem = ((blk*2+ks)*512) + ((n&15)*4 + ((d&31)>>3))*8 + (d&7)
//   vsw (A-frag of 16x16x16):       per (kblk=k>>4, df=d>>4) 256-elem tile,
//       elem = ((kblk*4+df)*256) + ((d&15)*4 + ((k&15)>>2))*4 + (k&3)
//
// ws layout (byte offsets):
//   0    stats float2[512] | 64K qwb bf16[1536*512] | 2M pwb bf16[512*512]
//   4M   hnt (B,N,C) bf16  (reused as ont)
//   20M  qsw | 36M ksw | 52M vsw   (16 MB each, 128 KB per (b,h))
// ---------------------------------------------------------------------------

typedef __bf16 bf16;
typedef __attribute__((ext_vector_type(8))) __bf16 bf16x8;
typedef __attribute__((ext_vector_type(4))) float f32x4;
typedef __attribute__((ext_vector_type(4))) short s16x4;

union U8 { uint4 u4; bf16x8 v; bf16 h[8]; };
union U4 { ushort4 u; bf16 h[4]; };
union UB4 { ushort4 u; s16x4 s; bf16 h[4]; };
union F4 { float4 v; float f[4]; };

typedef __attribute__((address_space(1))) void* gp1;
typedef __attribute__((address_space(3))) void* lp3;

__device__ __forceinline__ void async16(const void* g, void* l) {
  __builtin_amdgcn_global_load_lds((gp1)g, (lp3)l, 16, 0, 0);
}

#define LOG2E 1.44269504f

// ---------------------------------------------------------------------------
// Kernel 0: convert fp32 weights to bf16. qw: 1536x512, pw: 512x512.
// ---------------------------------------------------------------------------
__global__ __launch_bounds__(256) void cvt_w(const float* __restrict__ qw,
                                             const float* __restrict__ pw,
                                             bf16* __restrict__ qwb,
                                             bf16* __restrict__ pwb) {
  int i = blockIdx.x * 256 + threadIdx.x;     // float4 index; 262144 total
  F4 v; bf16* dst;
  if (i < 196608) { v.v = ((const float4*)qw)[i]; dst = qwb + (size_t)i * 4; }
  else { v.v = ((const float4*)pw)[i - 196608]; dst = pwb + (size_t)(i - 196608) * 4; }
  U4 o;
#pragma unroll
  for (int j = 0; j < 4; j++) o.h[j] = (bf16)v.f[j];
  *(ushort4*)dst = o.u;
}

// ---------------------------------------------------------------------------
// Kernel 1: per-(b,group) mean/rstd. One block per (b,g): 16ch x 1024 fp32.
// ---------------------------------------------------------------------------
__global__ __launch_bounds__(256) void gn_stats(const float* __restrict__ x,
                                                float2* __restrict__ stats) {
  int bg = blockIdx.x;                         // b*32 + g
  const float* base = x + (size_t)bg * 16384;
  int t = threadIdx.x;
  float s = 0.f, ss = 0.f;
#pragma unroll
  for (int p = 0; p < 16; p++) {
    F4 u; u.v = *(const float4*)(base + (size_t)(p * 256 + t) * 4);
#pragma unroll
    for (int i = 0; i < 4; i++) { float v = u.f[i]; s += v; ss += v * v; }
  }
  for (int off = 1; off < 64; off <<= 1) { s += __shfl_xor(s, off); ss += __shfl_xor(ss, off); }
  __shared__ float red[8];
  int w = t >> 6;
  if ((t & 63) == 0) { red[w] = s; red[4 + w] = ss; }
  __syncthreads();
  if (t == 0) {
    float S = red[0] + red[1] + red[2] + red[3];
    float SS = red[4] + red[5] + red[6] + red[7];
    float mean = S * (1.f / 16384.f);
    float var = SS * (1.f / 16384.f) - mean * mean;
    stats[bg] = make_float2(mean, rsqrtf(var + 1e-5f));
  }
}

// ---------------------------------------------------------------------------
// Kernel 2: hn_t[b][n][c] = bf16((x[b][c][n]-mean)*rstd*w + bias), transposed.
// ---------------------------------------------------------------------------
__global__ __launch_bounds__(256) void gn_apply(const float* __restrict__ x,
                                                const float* __restrict__ nwp,
                                                const float* __restrict__ nbp,
                                                const float2* __restrict__ stats,
                                                bf16* __restrict__ hnt) {
  int b = blockIdx.z, nt = blockIdx.y, ct = blockIdx.x;
  int t = threadIdx.x, w = t >> 6, l = t & 63;
  int wc = w & 1, wn = w >> 1;
  int cb = ct * 128 + wc * 64 + (l & 7) * 8;   // 8 channels per lane
  int n0 = nt * 64 + wn * 32 + (l >> 3) * 4;   // 4 n per lane
  float2 ms = stats[b * 32 + (cb >> 4)];
  float wgt[8], bia[8];
#pragma unroll
  for (int i = 0; i < 8; i++) {
    float wi = nwp[cb + i] * ms.y;
    wgt[i] = wi;
    bia[i] = nbp[cb + i] - ms.x * wi;
  }
  F4 in[8];
  const float* xb = x + ((size_t)b * 512 + cb) * 1024 + n0;
#pragma unroll
  for (int i = 0; i < 8; i++) in[i].v = *(const float4*)(xb + (size_t)i * 1024);
  bf16* ob = hnt + ((size_t)b * 1024 + n0) * 512 + cb;
#pragma unroll
  for (int j = 0; j < 4; j++) {
    U8 o;
#pragma unroll
    for (int i = 0; i < 8; i++) o.h[i] = (bf16)(in[i].f[j] * wgt[i] + bia[i]);
    *(uint4*)(ob + (size_t)j * 512) = o.u4;
  }
}

// ---------------------------------------------------------------------------
// Shared gemm-BT core (m97 recipe).
// ---------------------------------------------------------------------------
__device__ __forceinline__ void gemm_bt_core(const bf16* ga0, const bf16* gb0,
                                             bf16* At, bf16* Bt,
                                             f32x4 (&acc)[4][4], int w, int l) {
  const bf16* ga = ga0 + (size_t)(w * 16 + (l >> 2)) * 512 + (l & 3) * 8;
  const bf16* gb = gb0 + (size_t)(w * 16 + (l >> 2)) * 512 + (l & 3) * 8;
  int wr = w >> 1, wc = w & 1;
  const bf16* Ab = At + (wr * 64 + (l & 15)) * 32 + (l >> 4) * 8;
  const bf16* Bb = Bt + (wc * 64 + (l & 15)) * 32 + (l >> 4) * 8;
  bf16* lA = At + w * 16 * 32;
  bf16* lB = Bt + w * 16 * 32;
  for (int k0 = 0; k0 < 512; k0 += 32) {
    async16(ga + k0, lA);
    async16(ga + 64 * 512 + k0, lA + 64 * 32);
    async16(gb + k0, lB);
    async16(gb + 64 * 512 + k0, lB + 64 * 32);
    __syncthreads();
    bf16x8 af[4], bfr[4];
#pragma unroll
    for (int i = 0; i < 4; i++) {
      af[i] = *(const bf16x8*)(Ab + i * 512);
      bfr[i] = *(const bf16x8*)(Bb + i * 512);
    }
#pragma unroll
    for (int i = 0; i < 4; i++)
#pragma unroll
      for (int j = 0; j < 4; j++)
        acc[i][j] = __builtin_amdgcn_mfma_f32_16x16x32_bf16(af[i], bfr[j], acc[i][j], 0, 0, 0);
    __syncthreads();
  }
}

// ---------------------------------------------------------------------------
// Kernel 3: qkv projection GEMM; epilogue writes FRAGMENT-ORDERED q/k/v.
// Grid (ot=12, nt=8, b=16). ot 0..3 -> qsw, 4..7 -> ksw, 8..11 -> vsw.
// ---------------------------------------------------------------------------
__global__ __launch_bounds__(256, 2) void qkv_gemm(const bf16* __restrict__ hnt,
                                                   const bf16* __restrict__ qwb,
                                                   const float* __restrict__ qb,
                                                   bf16* __restrict__ qsw,
                                                   bf16* __restrict__ ksw,
                                                   bf16* __restrict__ vsw) {
  __shared__ bf16 At[128 * 32];
  __shared__ bf16 Bt[128 * 32];
  int b = blockIdx.z, mt = blockIdx.y, ot = blockIdx.x;
  int m0 = mt * 128, o0 = ot * 128;
  int t = threadIdx.x, w = t >> 6, l = t & 63;
  f32x4 acc[4][4] = {};
  gemm_bt_core(hnt + ((size_t)b * 1024 + m0) * 512, qwb + (size_t)o0 * 512, At, Bt, acc, w, l);

  int wr = w >> 1, wc = w & 1, quad = l >> 4, li = l & 15;
#pragma unroll
  for (int i = 0; i < 4; i++) {
    int gnb = m0 + wr * 64 + i * 16;      // 16-aligned n-block base
    int blk = gnb >> 4;                   // n-block (= k-block for K/V)
#pragma unroll
    for (int j = 0; j < 4; j++) {
      int go = o0 + wc * 64 + j * 16 + li;
      float bias = qb[go];
      if (ot < 8) {                       // q or k: frag-ordered 2B stores
        int c = (ot < 4) ? go : (go - 512);
        int hh = c >> 6, d = c & 63;
        int ks = d >> 5, dq = (d >> 3) & 3, jj = d & 7;
        bf16* base = ((ot < 4) ? qsw : ksw) + ((size_t)(b * 8 + hh) << 16)
                     + (blk * 2 + ks) * 512 + dq * 8 + jj;
#pragma unroll
        for (int r = 0; r < 4; r++)
          base[(quad * 4 + r) * 32] = (bf16)(acc[i][j][r] + bias);
      } else {                            // v: frag-ordered packed 8B stores
        int c = go - 1024;
        int hh = c >> 6, d = c & 63;
        int df = d >> 4, lv = d & 15;
        bf16* base = vsw + ((size_t)(b * 8 + hh) << 16)
                     + (blk * 4 + df) * 256 + (lv * 4 + quad) * 4;
        U4 pk;
#pragma unroll
        for (int r = 0; r < 4; r++) pk.h[r] = (bf16)(acc[i][j][r] + bias);
        *(ushort4*)base = pk.u;
      }
    }
  }
}

// ---------------------------------------------------------------------------
// Kernel 4: flash attention, S^T formulation, zero LDS, chunked softmax,
// fragment-ordered coalesced loads. Grid (bh=128, qt=8).
//
// Round-6: PHASE-STAGGER VIA s_sleep. Evidence across r0/r1/r4/r5: neither
// pipe exceeds ~40% busy, total busy <70%, and neither VALU diet (r1), more
// TLP (r4), nor in-wave pipelining (r5, setprio-pinned) moved dur. The one
// consistent explanation: co-resident waves are PHASE-LOCKED -- identical,
// jitter-free instruction cadence started simultaneously, so all waves
// convoy through the QK-MFMA burst together (VALU idle), then the softmax
// together (matrix idle). Fix: one-time deterministic s_sleep prologue,
// phase = cohort(blockIdx.y>>1, ids spaced 256 = co-resident)*4 + waveid,
// 16 phases x 128cy = 0..1920cy (~1.3 chunk periods). Zero math change
// (unlike r3's chunk-order stagger, which failed replay determinism),
// zero register cost. Keeps the r5 lean in-wave pipeline underneath.
// ---------------------------------------------------------------------------
__device__ __forceinline__ void attn_stage(const bf16* __restrict__ kp,
                                           const bf16* __restrict__ vp, int c,
                                           f32x4 (&stc)[2][2],   // in: S^T(c)
                                           f32x4 (&stn)[2][2],   // out: S^T(c+1)
                                           U8 (&ka)[2], U8 (&kc)[2],  // K(c+1) in / K(c+2) out
                                           const bf16x8 (&qfr)[2][2],
                                           float (&mrun)[2], f32x4 (&lacc)[2],
                                           f32x4 (&of)[4][2]) {
  // ---- QK^T(c+1): fills the matrix pipe while softmax(c) runs below ----
#pragma unroll
  for (int qf = 0; qf < 2; qf++)
#pragma unroll
    for (int kf = 0; kf < 2; kf++) stn[qf][kf] = (f32x4){0.f, 0.f, 0.f, 0.f};
  __builtin_amdgcn_s_setprio(1);
#pragma unroll
  for (int kf = 0; kf < 2; kf++) {
    stn[0][kf] = __builtin_amdgcn_mfma_f32_16x16x32_bf16(ka[kf].v, qfr[0][0], stn[0][kf], 0, 0, 0);
    stn[1][kf] = __builtin_amdgcn_mfma_f32_16x16x32_bf16(ka[kf].v, qfr[1][0], stn[1][kf], 0, 0, 0);
    stn[0][kf] = __builtin_amdgcn_mfma_f32_16x16x32_bf16(kc[kf].v, qfr[0][1], stn[0][kf], 0, 0, 0);
    stn[1][kf] = __builtin_amdgcn_mfma_f32_16x16x32_bf16(kc[kf].v, qfr[1][1], stn[1][kf], 0, 0, 0);
  }
  __builtin_amdgcn_s_setprio(0);
  int cb = c * 2048;
  // ---- V(c): consumed by PV at stage end (~600 cy of cover) ----
  UB4 va[2][4];
#pragma unroll
  for (int kf = 0; kf < 2; kf++)
#pragma unroll
    for (int df = 0; df < 4; df++)
      va[kf][df].u = *(const ushort4*)(vp + cb + kf * 1024 + df * 256);
  // ---- K(c+2) into the SAME regs (QK(c+1) already consumed them) ----
  int cn = ((c + 2) & 31) * 2048;
#pragma unroll
  for (int kf = 0; kf < 2; kf++) {
    ka[kf].u4 = *(const uint4*)(kp + cn + kf * 1024);
    kc[kf].u4 = *(const uint4*)(kp + cn + kf * 1024 + 512);
  }
  // ---- softmax(c) on stc, defer-max (THR=8 in log2 domain) ----
  UB4 pfr[2][2];
#pragma unroll
  for (int qf = 0; qf < 2; qf++) {
    float mt = fmaxf(fmaxf(fmaxf(stc[qf][0][0], stc[qf][0][1]),
                           fmaxf(stc[qf][0][2], stc[qf][0][3])),
                     fmaxf(fmaxf(stc[qf][1][0], stc[qf][1][1]),
                           fmaxf(stc[qf][1][2], stc[qf][1][3])));
    if (__ballot(mt > mrun[qf] + 8.f)) {     // rare: ~first chunk only
      mt = fmaxf(mt, __shfl_xor(mt, 16));
      mt = fmaxf(mt, __shfl_xor(mt, 32));
      float mnew = fmaxf(mrun[qf], mt);
      float alpha = __builtin_amdgcn_exp2f(mrun[qf] - mnew);
      mrun[qf] = mnew;
#pragma unroll
      for (int r = 0; r < 4; r++) lacc[qf][r] *= alpha;
#pragma unroll
      for (int df = 0; df < 4; df++)
#pragma unroll
        for (int r = 0; r < 4; r++) of[df][qf][r] *= alpha;
    }
    float m = mrun[qf];
#pragma unroll
    for (int kf = 0; kf < 2; kf++)
#pragma unroll
      for (int r = 0; r < 4; r++) {
        float e = __builtin_amdgcn_exp2f(stc[qf][kf][r] - m);   // <= 2^8
        lacc[qf][r] += e;
        pfr[qf][kf].h[r] = (bf16)e;
      }
  }
  // ---- PV(c): O^T += V^T P^T (16x16x16, P^T straight from registers) ----
  __builtin_amdgcn_s_setprio(1);
#pragma unroll
  for (int kf = 0; kf < 2; kf++)
#pragma unroll
    for (int df = 0; df < 4; df++)
#pragma unroll
      for (int qf = 0; qf < 2; qf++)
        of[df][qf] = __builtin_amdgcn_mfma_f32_16x16x16bf16_1k(va[kf][df].s, pfr[qf][kf].s, of[df][qf], 0, 0, 0);
  __builtin_amdgcn_s_setprio(0);
}

__global__ __launch_bounds__(256, 3) void attn(const bf16* __restrict__ qsw,
                                               const bf16* __restrict__ ksw,
                                               const bf16* __restrict__ vsw,
                                               bf16* __restrict__ ont) {
  int bh = blockIdx.x;                 // b*8 + h
  int b = bh >> 3, h = bh & 7;
  int qt = blockIdx.y;
  int t = threadIdx.x, w = t >> 6, l = t & 63;
  int quad = l >> 4, li = l & 15;
  int q0 = qt * 128 + w * 32;

  // ---- phase stagger: decorrelate co-resident waves' pipeline phases.
  //      cohort = qt>>1 (co-resident block ids are spaced by 256 in this
  //      1024-block grid), 4 cohorts x 4 waves = 16 phases x ~128cy.
  //      Deterministic, no math change, one-time cost <1us. ----
  int ph = (((qt >> 1) & 3) << 2) | w;
  for (int i = 0; i < ph; ++i) __builtin_amdgcn_s_sleep(2);

  int laneK = (li * 4 + quad) * 8;     // 16B-chunk lane offset (elems)
  int laneV = (li * 4 + quad) * 4;     // 8B-chunk lane offset (elems)
  const bf16* qp = qsw + ((size_t)bh << 16) + laneK;
  const bf16* kp = ksw + ((size_t)bh << 16) + laneK;
  const bf16* vp = vsw + ((size_t)bh << 16) + laneV;

  // Q frags (B-operand of 16x16x32): scale = 0.125 * log2(e) folded in.
  const float QS = 0.125f * LOG2E;
  bf16x8 qfr[2][2];
#pragma unroll
  for (int qf = 0; qf < 2; qf++)
#pragma unroll
    for (int ks = 0; ks < 2; ks++) {
      U8 u;
      u.u4 = *(const uint4*)(qp + (((q0 >> 4) + qf) * 2 + ks) * 512);
#pragma unroll
      for (int i = 0; i < 8; i++) u.h[i] = (bf16)((float)u.h[i] * QS);
      qfr[qf][ks] = u.v;
    }

  float mrun[2] = {-INFINITY, -INFINITY};
  f32x4 lacc[2] = {};    // per-lane partial exp sums (reduced in epilogue)
  f32x4 of[4][2] = {};   // O^T accum [df][qf]: row d=df*16+quad*4+r, col q=qf*16+li

  // ---- prologue: K(0) -> regs; QK^T(0) -> st0; issue K(1) load ----
  U8 ka[2], kc[2];
#pragma unroll
  for (int kf = 0; kf < 2; kf++) {
    ka[kf].u4 = *(const uint4*)(kp + kf * 1024);
    kc[kf].u4 = *(const uint4*)(kp + kf * 1024 + 512);
  }
  f32x4 st0[2][2] = {}, st1[2][2];
  __builtin_amdgcn_s_setprio(1);
#pragma unroll
  for (int kf = 0; kf < 2; kf++) {
    st0[0][kf] = __builtin_amdgcn_mfma_f32_16x16x32_bf16(ka[kf].v, qfr[0][0], st0[0][kf], 0, 0, 0);
    st0[1][kf] = __builtin_amdgcn_mfma_f32_16x16x32_bf16(ka[kf].v, qfr[1][0], st0[1][kf], 0, 0, 0);
    st0[0][kf] = __builtin_amdgcn_mfma_f32_16x16x32_bf16(kc[kf].v, qfr[0][1], st0[0][kf], 0, 0, 0);
    st0[1][kf] = __builtin_amdgcn_mfma_f32_16x16x32_bf16(kc[kf].v, qfr[1][1], st0[1][kf], 0, 0, 0);
  }
  __builtin_amdgcn_s_setprio(0);
#pragma unroll
  for (int kf = 0; kf < 2; kf++) {     // K(1) into the same regs
    ka[kf].u4 = *(const uint4*)(kp + 2048 + kf * 1024);
    kc[kf].u4 = *(const uint4*)(kp + 2048 + kf * 1024 + 512);
  }

  // ---- pipelined main loop: stage(c) = QK(c+1) || softmax(c) -> PV(c).
  //      x2 unroll keeps the st ping-pong indices static. ----
  for (int c = 0; c < 32; c += 2) {
    attn_stage(kp, vp, c,     st0, st1, ka, kc, qfr, mrun, lacc, of);
    attn_stage(kp, vp, c + 1, st1, st0, ka, kc, qfr, mrun, lacc, of);
  }

  // ---- epilogue: single cross-lane l reduce, O[q][d] = O^T/l ----
#pragma unroll
  for (int qf = 0; qf < 2; qf++) {
    float lsum = (lacc[qf][0] + lacc[qf][1]) + (lacc[qf][2] + lacc[qf][3]);
    lsum += __shfl_xor(lsum, 16);
    lsum += __shfl_xor(lsum, 32);
    float inv = 1.f / lsum;
    bf16* ob = ont + ((size_t)b * 1024 + q0 + qf * 16 + li) * 512 + h * 64 + quad * 4;
#pragma unroll
    for (int df = 0; df < 4; df++) {
      U4 pk;
#pragma unroll
      for (int r = 0; r < 4; r++) pk.h[r] = (bf16)(of[df][qf][r] * inv);
      *(ushort4*)(ob + df * 16) = pk.u;
    }
  }
}

// ---------------------------------------------------------------------------
// Kernel 5: proj GEMM + residual. Grid (4, 8, 16).
// ---------------------------------------------------------------------------
__global__ __launch_bounds__(256, 2) void proj_gemm(const bf16* __restrict__ ont,
                                                    const bf16* __restrict__ pwb,
                                                    const float* __restrict__ pb,
                                                    const float* __restrict__ x,
                                                    float* __restrict__ out) {
  __shared__ bf16 At[128 * 32];
  __shared__ bf16 Bt[128 * 32];
  int b = blockIdx.z, mt = blockIdx.y, ot = blockIdx.x;
  int m0 = mt * 128, o0 = ot * 128;
  int t = threadIdx.x, w = t >> 6, l = t & 63;
  f32x4 acc[4][4] = {};
  gemm_bt_core(ont + ((size_t)b * 1024 + m0) * 512, pwb + (size_t)o0 * 512, At, Bt, acc, w, l);

  int wr = w >> 1, wc = w & 1, quad = l >> 4, li = l & 15;
#pragma unroll
  for (int i = 0; i < 4; i++) {
    int gn = m0 + wr * 64 + i * 16 + quad * 4;
#pragma unroll
    for (int j = 0; j < 4; j++) {
      int go = o0 + wc * 64 + j * 16 + li;
      float bias = pb[go];
      F4 xres; xres.v = *(const float4*)(x + ((size_t)b * 512 + go) * 1024 + gn);
      F4 o;
#pragma unroll
      for (int r = 0; r < 4; r++) o.f[r] = acc[i][j][r] + bias + xres.f[r];
      *(float4*)(out + ((size_t)b * 512 + go) * 1024 + gn) = o.v;
    }
  }
}

// ---------------------------------------------------------------------------
extern "C" void kernel_launch(void* const* d_in, const int* in_sizes, int n_in,
                              void* d_out, int out_size, void* d_ws, size_t ws_size,
                              hipStream_t stream) {
  const float* x  = (const float*)d_in[0];
  const float* nw = (const float*)d_in[1];
  const float* nb = (const float*)d_in[2];
  const float* qw = (const float*)d_in[3];
  const float* qb = (const float*)d_in[4];
  const float* pw = (const float*)d_in[5];
  const float* pb = (const float*)d_in[6];
  float* out = (float*)d_out;

  char* ws = (char*)d_ws;
  float2* stats = (float2*)ws;
  bf16* qwb = (bf16*)(ws + (64u << 10));
  bf16* pwb = (bf16*)(ws + (2u << 20));
  bf16* hnt = (bf16*)(ws + (4u << 20));   // reused as ont after qkv_gemm
  bf16* qsw = (bf16*)(ws + (20u << 20));
  bf16* ksw = (bf16*)(ws + (36u << 20));
  bf16* vsw = (bf16*)(ws + (52u << 20));
  bf16* ont = hnt;

  cvt_w<<<1024, 256, 0, stream>>>(qw, pw, qwb, pwb);
  gn_stats<<<512, 256, 0, stream>>>(x, stats);
  gn_apply<<<dim3(4, 16, 16), 256, 0, stream>>>(x, nw, nb, stats, hnt);
  qkv_gemm<<<dim3(12, 8, 16), 256, 0, stream>>>(hnt, qwb, qb, qsw, ksw, vsw);
  attn<<<dim3(128, 8, 1), 256, 0, stream>>>(qsw, ksw, vsw, ont);
  proj_gemm<<<dim3(4, 8, 16), 256, 0, stream>>>(ont, pwb, pb, x, out);
}

// Round 7
// 230.080 us; speedup vs baseline: 1.0071x; 1.0071x over previous
//
#include <hip/hip_runtime.h>
#include <cstdint>
#include <math.h>

// ---------------------------------------------------------------------------
// AttentionBlock: GroupNorm(32) -> 1x1 conv QKV -> MHA(8 heads, hd=64)
//                 -> 1x1 conv proj -> +residual.   B=16, C=512, N=H*W=1024.
// I/O tensors are FP32. Internal math: bf16 MFMA.
//
// Q/K/V are stored FRAGMENT-ORDERED per (b,h) so attention loads are fully
// coalesced single-burst reads:
//   qsw/ksw (A/B-frag of 16x16x32): per (blk=n>>4, ks=d>>5) 512-elem tile,
//       elem = ((blk*2+ks)*512) + ((n&15)*4 + ((d&31)>>3))*8 + (d&7)
//   vsw (A-frag of 16x16x16):       per (kblk=k>>4, df=d>>4) 256-elem tile,
//       elem = ((kblk*4+df)*256) + ((d&15)*4 + ((k&15)>>2))*4 + (k&3)
//
// ws layout (byte offsets):
//   0    stats float2[512] | 64K qwb bf16[1536*512] | 2M pwb bf16[512*512]
//   4M   hnt (B,N,C) bf16  (reused as ont)
//   20M  qsw | 36M ksw | 52M vsw   (16 MB each, 128 KB per (b,h))
// ---------------------------------------------------------------------------

typedef __bf16 bf16;
typedef __attribute__((ext_vector_type(8))) __bf16 bf16x8;
typedef __attribute__((ext_vector_type(4))) float f32x4;
typedef __attribute__((ext_vector_type(4))) short s16x4;

union U8 { uint4 u4; bf16x8 v; bf16 h[8]; };
union U4 { ushort4 u; bf16 h[4]; };
union UB4 { ushort4 u; s16x4 s; bf16 h[4]; };
union F4 { float4 v; float f[4]; };

typedef __attribute__((address_space(1))) void* gp1;
typedef __attribute__((address_space(3))) void* lp3;

__device__ __forceinline__ void async16(const void* g, void* l) {
  __builtin_amdgcn_global_load_lds((gp1)g, (lp3)l, 16, 0, 0);
}

#define LOG2E 1.44269504f

// ---------------------------------------------------------------------------
// Kernel 0: convert fp32 weights to bf16. qw: 1536x512, pw: 512x512.
// ---------------------------------------------------------------------------
__global__ __launch_bounds__(256) void cvt_w(const float* __restrict__ qw,
                                             const float* __restrict__ pw,
                                             bf16* __restrict__ qwb,
                                             bf16* __restrict__ pwb) {
  int i = blockIdx.x * 256 + threadIdx.x;     // float4 index; 262144 total
  F4 v; bf16* dst;
  if (i < 196608) { v.v = ((const float4*)qw)[i]; dst = qwb + (size_t)i * 4; }
  else { v.v = ((const float4*)pw)[i - 196608]; dst = pwb + (size_t)(i - 196608) * 4; }
  U4 o;
#pragma unroll
  for (int j = 0; j < 4; j++) o.h[j] = (bf16)v.f[j];
  *(ushort4*)dst = o.u;
}

// ---------------------------------------------------------------------------
// Kernel 1: per-(b,group) mean/rstd. One block per (b,g): 16ch x 1024 fp32.
// ---------------------------------------------------------------------------
__global__ __launch_bounds__(256) void gn_stats(const float* __restrict__ x,
                                                float2* __restrict__ stats) {
  int bg = blockIdx.x;                         // b*32 + g
  const float* base = x + (size_t)bg * 16384;
  int t = threadIdx.x;
  float s = 0.f, ss = 0.f;
#pragma unroll
  for (int p = 0; p < 16; p++) {
    F4 u; u.v = *(const float4*)(base + (size_t)(p * 256 + t) * 4);
#pragma unroll
    for (int i = 0; i < 4; i++) { float v = u.f[i]; s += v; ss += v * v; }
  }
  for (int off = 1; off < 64; off <<= 1) { s += __shfl_xor(s, off); ss += __shfl_xor(ss, off); }
  __shared__ float red[8];
  int w = t >> 6;
  if ((t & 63) == 0) { red[w] = s; red[4 + w] = ss; }
  __syncthreads();
  if (t == 0) {
    float S = red[0] + red[1] + red[2] + red[3];
    float SS = red[4] + red[5] + red[6] + red[7];
    float mean = S * (1.f / 16384.f);
    float var = SS * (1.f / 16384.f) - mean * mean;
    stats[bg] = make_float2(mean, rsqrtf(var + 1e-5f));
  }
}

// ---------------------------------------------------------------------------
// Kernel 2: hn_t[b][n][c] = bf16((x[b][c][n]-mean)*rstd*w + bias), transposed.
// ---------------------------------------------------------------------------
__global__ __launch_bounds__(256) void gn_apply(const float* __restrict__ x,
                                                const float* __restrict__ nwp,
                                                const float* __restrict__ nbp,
                                                const float2* __restrict__ stats,
                                                bf16* __restrict__ hnt) {
  int b = blockIdx.z, nt = blockIdx.y, ct = blockIdx.x;
  int t = threadIdx.x, w = t >> 6, l = t & 63;
  int wc = w & 1, wn = w >> 1;
  int cb = ct * 128 + wc * 64 + (l & 7) * 8;   // 8 channels per lane
  int n0 = nt * 64 + wn * 32 + (l >> 3) * 4;   // 4 n per lane
  float2 ms = stats[b * 32 + (cb >> 4)];
  float wgt[8], bia[8];
#pragma unroll
  for (int i = 0; i < 8; i++) {
    float wi = nwp[cb + i] * ms.y;
    wgt[i] = wi;
    bia[i] = nbp[cb + i] - ms.x * wi;
  }
  F4 in[8];
  const float* xb = x + ((size_t)b * 512 + cb) * 1024 + n0;
#pragma unroll
  for (int i = 0; i < 8; i++) in[i].v = *(const float4*)(xb + (size_t)i * 1024);
  bf16* ob = hnt + ((size_t)b * 1024 + n0) * 512 + cb;
#pragma unroll
  for (int j = 0; j < 4; j++) {
    U8 o;
#pragma unroll
    for (int i = 0; i < 8; i++) o.h[i] = (bf16)(in[i].f[j] * wgt[i] + bia[i]);
    *(uint4*)(ob + (size_t)j * 512) = o.u4;
  }
}

// ---------------------------------------------------------------------------
// Shared gemm-BT core, 2-PHASE DOUBLE-BUFFERED (round-7).
// Old core was single-buffered: stage(k) -> barrier[vmcnt(0) drain] ->
// MFMA(k) -> barrier. Every K-step paid the full staging latency serially
// before any compute, 16x, at ~2 waves/SIMD TLP. New core: stage(k+1)
// issued BEFORE compute(k); ONE barrier per K-step (its vmcnt(0) drain
// lands after the MFMAs, so staging latency hides under compute). This is
// the T3-catalog "minimum 2-phase" recipe. LDS: 2x(A,B) = 32 KB.
// ---------------------------------------------------------------------------
__device__ __forceinline__ void gemm_compute32(const bf16* __restrict__ rA,
                                               const bf16* __restrict__ rB,
                                               int aoff, int boff,
                                               f32x4 (&acc)[4][4]) {
  bf16x8 af[4], bfr[4];
#pragma unroll
  for (int i = 0; i < 4; i++) {
    af[i] = *(const bf16x8*)(rA + aoff + i * 512);
    bfr[i] = *(const bf16x8*)(rB + boff + i * 512);
  }
#pragma unroll
  for (int i = 0; i < 4; i++)
#pragma unroll
    for (int j = 0; j < 4; j++)
      acc[i][j] = __builtin_amdgcn_mfma_f32_16x16x32_bf16(af[i], bfr[j], acc[i][j], 0, 0, 0);
}

__device__ __forceinline__ void gemm_bt_core(const bf16* ga0, const bf16* gb0,
                                             bf16* A0, bf16* B0,
                                             bf16* A1, bf16* B1,
                                             f32x4 (&acc)[4][4], int w, int l) {
  const bf16* ga = ga0 + (size_t)(w * 16 + (l >> 2)) * 512 + (l & 3) * 8;
  const bf16* gb = gb0 + (size_t)(w * 16 + (l >> 2)) * 512 + (l & 3) * 8;
  int wr = w >> 1, wc = w & 1;
  int aoff = (wr * 64 + (l & 15)) * 32 + (l >> 4) * 8;
  int boff = (wc * 64 + (l & 15)) * 32 + (l >> 4) * 8;
  int soff = w * 16 * 32;              // this wave's staging slice

  // ---- prologue: stage k=0 into buf0 ----
  async16(ga, A0 + soff);
  async16(ga + 64 * 512, A0 + soff + 64 * 32);
  async16(gb, B0 + soff);
  async16(gb + 64 * 512, B0 + soff + 64 * 32);
  __syncthreads();                     // vmcnt(0) drain + barrier

  for (int k0 = 0; k0 < 512; k0 += 64) {
    // ---- phase A: stage k0+32 -> buf1, compute k0 from buf0 ----
    async16(ga + k0 + 32, A1 + soff);
    async16(ga + 64 * 512 + k0 + 32, A1 + soff + 64 * 32);
    async16(gb + k0 + 32, B1 + soff);
    async16(gb + 64 * 512 + k0 + 32, B1 + soff + 64 * 32);
    gemm_compute32(A0, B0, aoff, boff, acc);
    __syncthreads();                   // drain buf1 loads; protect buf0 reuse
    // ---- phase B: stage k0+64 -> buf0 (guarded), compute k0+32 from buf1 --
    if (k0 + 64 < 512) {
      async16(ga + k0 + 64, A0 + soff);
      async16(ga + 64 * 512 + k0 + 64, A0 + soff + 64 * 32);
      async16(gb + k0 + 64, B0 + soff);
      async16(gb + 64 * 512 + k0 + 64, B0 + soff + 64 * 32);
    }
    gemm_compute32(A1, B1, aoff, boff, acc);
    __syncthreads();                   // drain buf0 loads; protect buf1 reuse
  }
}

// ---------------------------------------------------------------------------
// Kernel 3: qkv projection GEMM; epilogue writes FRAGMENT-ORDERED q/k/v.
// Grid (ot=12, nt=8, b=16). ot 0..3 -> qsw, 4..7 -> ksw, 8..11 -> vsw.
// ---------------------------------------------------------------------------
__global__ __launch_bounds__(256, 3) void qkv_gemm(const bf16* __restrict__ hnt,
                                                   const bf16* __restrict__ qwb,
                                                   const float* __restrict__ qb,
                                                   bf16* __restrict__ qsw,
                                                   bf16* __restrict__ ksw,
                                                   bf16* __restrict__ vsw) {
  __shared__ bf16 A0[128 * 32], B0[128 * 32], A1[128 * 32], B1[128 * 32];
  int b = blockIdx.z, mt = blockIdx.y, ot = blockIdx.x;
  int m0 = mt * 128, o0 = ot * 128;
  int t = threadIdx.x, w = t >> 6, l = t & 63;
  f32x4 acc[4][4] = {};
  gemm_bt_core(hnt + ((size_t)b * 1024 + m0) * 512, qwb + (size_t)o0 * 512,
               A0, B0, A1, B1, acc, w, l);

  int wr = w >> 1, wc = w & 1, quad = l >> 4, li = l & 15;
#pragma unroll
  for (int i = 0; i < 4; i++) {
    int gnb = m0 + wr * 64 + i * 16;      // 16-aligned n-block base
    int blk = gnb >> 4;                   // n-block (= k-block for K/V)
#pragma unroll
    for (int j = 0; j < 4; j++) {
      int go = o0 + wc * 64 + j * 16 + li;
      float bias = qb[go];
      if (ot < 8) {                       // q or k: frag-ordered 2B stores
        int c = (ot < 4) ? go : (go - 512);
        int hh = c >> 6, d = c & 63;
        int ks = d >> 5, dq = (d >> 3) & 3, jj = d & 7;
        bf16* base = ((ot < 4) ? qsw : ksw) + ((size_t)(b * 8 + hh) << 16)
                     + (blk * 2 + ks) * 512 + dq * 8 + jj;
#pragma unroll
        for (int r = 0; r < 4; r++)
          base[(quad * 4 + r) * 32] = (bf16)(acc[i][j][r] + bias);
      } else {                            // v: frag-ordered packed 8B stores
        int c = go - 1024;
        int hh = c >> 6, d = c & 63;
        int df = d >> 4, lv = d & 15;
        bf16* base = vsw + ((size_t)(b * 8 + hh) << 16)
                     + (blk * 4 + df) * 256 + (lv * 4 + quad) * 4;
        U4 pk;
#pragma unroll
        for (int r = 0; r < 4; r++) pk.h[r] = (bf16)(acc[i][j][r] + bias);
        *(ushort4*)base = pk.u;
      }
    }
  }
}

// ---------------------------------------------------------------------------
// Kernel 4: flash attention, S^T formulation, zero LDS, chunked softmax,
// fragment-ordered coalesced loads. Grid (bh=128, qt=8).
//
// Round-7: attn = round-5 structure exactly (r6's s_sleep stagger REVERTED:
// it cost 11us -- desynchronizing waves hurt, lockstep theory falsified;
// the synchronized cadence was L2-friendly). attn is plateaued at ~78us
// across 6 structural attempts; this round attacks the GEMMs instead.
// ---------------------------------------------------------------------------
__device__ __forceinline__ void attn_stage(const bf16* __restrict__ kp,
                                           const bf16* __restrict__ vp, int c,
                                           f32x4 (&stc)[2][2],   // in: S^T(c)
                                           f32x4 (&stn)[2][2],   // out: S^T(c+1)
                                           U8 (&ka)[2], U8 (&kc)[2],  // K(c+1) in / K(c+2) out
                                           const bf16x8 (&qfr)[2][2],
                                           float (&mrun)[2], f32x4 (&lacc)[2],
                                           f32x4 (&of)[4][2]) {
  // ---- QK^T(c+1): fills the matrix pipe while softmax(c) runs below ----
#pragma unroll
  for (int qf = 0; qf < 2; qf++)
#pragma unroll
    for (int kf = 0; kf < 2; kf++) stn[qf][kf] = (f32x4){0.f, 0.f, 0.f, 0.f};
  __builtin_amdgcn_s_setprio(1);
#pragma unroll
  for (int kf = 0; kf < 2; kf++) {
    stn[0][kf] = __builtin_amdgcn_mfma_f32_16x16x32_bf16(ka[kf].v, qfr[0][0], stn[0][kf], 0, 0, 0);
    stn[1][kf] = __builtin_amdgcn_mfma_f32_16x16x32_bf16(ka[kf].v, qfr[1][0], stn[1][kf], 0, 0, 0);
    stn[0][kf] = __builtin_amdgcn_mfma_f32_16x16x32_bf16(kc[kf].v, qfr[0][1], stn[0][kf], 0, 0, 0);
    stn[1][kf] = __builtin_amdgcn_mfma_f32_16x16x32_bf16(kc[kf].v, qfr[1][1], stn[1][kf], 0, 0, 0);
  }
  __builtin_amdgcn_s_setprio(0);
  int cb = c * 2048;
  // ---- V(c): consumed by PV at stage end (~600 cy of cover) ----
  UB4 va[2][4];
#pragma unroll
  for (int kf = 0; kf < 2; kf++)
#pragma unroll
    for (int df = 0; df < 4; df++)
      va[kf][df].u = *(const ushort4*)(vp + cb + kf * 1024 + df * 256);
  // ---- K(c+2) into the SAME regs (QK(c+1) already consumed them) ----
  int cn = ((c + 2) & 31) * 2048;
#pragma unroll
  for (int kf = 0; kf < 2; kf++) {
    ka[kf].u4 = *(const uint4*)(kp + cn + kf * 1024);
    kc[kf].u4 = *(const uint4*)(kp + cn + kf * 1024 + 512);
  }
  // ---- softmax(c) on stc, defer-max (THR=8 in log2 domain) ----
  UB4 pfr[2][2];
#pragma unroll
  for (int qf = 0; qf < 2; qf++) {
    float mt = fmaxf(fmaxf(fmaxf(stc[qf][0][0], stc[qf][0][1]),
                           fmaxf(stc[qf][0][2], stc[qf][0][3])),
                     fmaxf(fmaxf(stc[qf][1][0], stc[qf][1][1]),
                           fmaxf(stc[qf][1][2], stc[qf][1][3])));
    if (__ballot(mt > mrun[qf] + 8.f)) {     // rare: ~first chunk only
      mt = fmaxf(mt, __shfl_xor(mt, 16));
      mt = fmaxf(mt, __shfl_xor(mt, 32));
      float mnew = fmaxf(mrun[qf], mt);
      float alpha = __builtin_amdgcn_exp2f(mrun[qf] - mnew);
      mrun[qf] = mnew;
#pragma unroll
      for (int r = 0; r < 4; r++) lacc[qf][r] *= alpha;
#pragma unroll
      for (int df = 0; df < 4; df++)
#pragma unroll
        for (int r = 0; r < 4; r++) of[df][qf][r] *= alpha;
    }
    float m = mrun[qf];
#pragma unroll
    for (int kf = 0; kf < 2; kf++)
#pragma unroll
      for (int r = 0; r < 4; r++) {
        float e = __builtin_amdgcn_exp2f(stc[qf][kf][r] - m);   // <= 2^8
        lacc[qf][r] += e;
        pfr[qf][kf].h[r] = (bf16)e;
      }
  }
  // ---- PV(c): O^T += V^T P^T (16x16x16, P^T straight from registers) ----
  __builtin_amdgcn_s_setprio(1);
#pragma unroll
  for (int kf = 0; kf < 2; kf++)
#pragma unroll
    for (int df = 0; df < 4; df++)
#pragma unroll
      for (int qf = 0; qf < 2; qf++)
        of[df][qf] = __builtin_amdgcn_mfma_f32_16x16x16bf16_1k(va[kf][df].s, pfr[qf][kf].s, of[df][qf], 0, 0, 0);
  __builtin_amdgcn_s_setprio(0);
}

__global__ __launch_bounds__(256, 3) void attn(const bf16* __restrict__ qsw,
                                               const bf16* __restrict__ ksw,
                                               const bf16* __restrict__ vsw,
                                               bf16* __restrict__ ont) {
  int bh = blockIdx.x;                 // b*8 + h
  int b = bh >> 3, h = bh & 7;
  int qt = blockIdx.y;
  int t = threadIdx.x, w = t >> 6, l = t & 63;
  int quad = l >> 4, li = l & 15;
  int q0 = qt * 128 + w * 32;

  int laneK = (li * 4 + quad) * 8;     // 16B-chunk lane offset (elems)
  int laneV = (li * 4 + quad) * 4;     // 8B-chunk lane offset (elems)
  const bf16* qp = qsw + ((size_t)bh << 16) + laneK;
  const bf16* kp = ksw + ((size_t)bh << 16) + laneK;
  const bf16* vp = vsw + ((size_t)bh << 16) + laneV;

  // Q frags (B-operand of 16x16x32): scale = 0.125 * log2(e) folded in.
  const float QS = 0.125f * LOG2E;
  bf16x8 qfr[2][2];
#pragma unroll
  for (int qf = 0; qf < 2; qf++)
#pragma unroll
    for (int ks = 0; ks < 2; ks++) {
      U8 u;
      u.u4 = *(const uint4*)(qp + (((q0 >> 4) + qf) * 2 + ks) * 512);
#pragma unroll
      for (int i = 0; i < 8; i++) u.h[i] = (bf16)((float)u.h[i] * QS);
      qfr[qf][ks] = u.v;
    }

  float mrun[2] = {-INFINITY, -INFINITY};
  f32x4 lacc[2] = {};    // per-lane partial exp sums (reduced in epilogue)
  f32x4 of[4][2] = {};   // O^T accum [df][qf]: row d=df*16+quad*4+r, col q=qf*16+li

  // ---- prologue: K(0) -> regs; QK^T(0) -> st0; issue K(1) load ----
  U8 ka[2], kc[2];
#pragma unroll
  for (int kf = 0; kf < 2; kf++) {
    ka[kf].u4 = *(const uint4*)(kp + kf * 1024);
    kc[kf].u4 = *(const uint4*)(kp + kf * 1024 + 512);
  }
  f32x4 st0[2][2] = {}, st1[2][2];
  __builtin_amdgcn_s_setprio(1);
#pragma unroll
  for (int kf = 0; kf < 2; kf++) {
    st0[0][kf] = __builtin_amdgcn_mfma_f32_16x16x32_bf16(ka[kf].v, qfr[0][0], st0[0][kf], 0, 0, 0);
    st0[1][kf] = __builtin_amdgcn_mfma_f32_16x16x32_bf16(ka[kf].v, qfr[1][0], st0[1][kf], 0, 0, 0);
    st0[0][kf] = __builtin_amdgcn_mfma_f32_16x16x32_bf16(kc[kf].v, qfr[0][1], st0[0][kf], 0, 0, 0);
    st0[1][kf] = __builtin_amdgcn_mfma_f32_16x16x32_bf16(kc[kf].v, qfr[1][1], st0[1][kf], 0, 0, 0);
  }
  __builtin_amdgcn_s_setprio(0);
#pragma unroll
  for (int kf = 0; kf < 2; kf++) {     // K(1) into the same regs
    ka[kf].u4 = *(const uint4*)(kp + 2048 + kf * 1024);
    kc[kf].u4 = *(const uint4*)(kp + 2048 + kf * 1024 + 512);
  }

  // ---- pipelined main loop: stage(c) = QK(c+1) || softmax(c) -> PV(c).
  //      x2 unroll keeps the st ping-pong indices static. ----
  for (int c = 0; c < 32; c += 2) {
    attn_stage(kp, vp, c,     st0, st1, ka, kc, qfr, mrun, lacc, of);
    attn_stage(kp, vp, c + 1, st1, st0, ka, kc, qfr, mrun, lacc, of);
  }

  // ---- epilogue: single cross-lane l reduce, O[q][d] = O^T/l ----
#pragma unroll
  for (int qf = 0; qf < 2; qf++) {
    float lsum = (lacc[qf][0] + lacc[qf][1]) + (lacc[qf][2] + lacc[qf][3]);
    lsum += __shfl_xor(lsum, 16);
    lsum += __shfl_xor(lsum, 32);
    float inv = 1.f / lsum;
    bf16* ob = ont + ((size_t)b * 1024 + q0 + qf * 16 + li) * 512 + h * 64 + quad * 4;
#pragma unroll
    for (int df = 0; df < 4; df++) {
      U4 pk;
#pragma unroll
      for (int r = 0; r < 4; r++) pk.h[r] = (bf16)(of[df][qf][r] * inv);
      *(ushort4*)(ob + df * 16) = pk.u;
    }
  }
}

// ---------------------------------------------------------------------------
// Kernel 5: proj GEMM + residual. Grid (4, 8, 16).
// ---------------------------------------------------------------------------
__global__ __launch_bounds__(256, 3) void proj_gemm(const bf16* __restrict__ ont,
                                                    const bf16* __restrict__ pwb,
                                                    const float* __restrict__ pb,
                                                    const float* __restrict__ x,
                                                    float* __restrict__ out) {
  __shared__ bf16 A0[128 * 32], B0[128 * 32], A1[128 * 32], B1[128 * 32];
  int b = blockIdx.z, mt = blockIdx.y, ot = blockIdx.x;
  int m0 = mt * 128, o0 = ot * 128;
  int t = threadIdx.x, w = t >> 6, l = t & 63;
  f32x4 acc[4][4] = {};
  gemm_bt_core(ont + ((size_t)b * 1024 + m0) * 512, pwb + (size_t)o0 * 512,
               A0, B0, A1, B1, acc, w, l);

  int wr = w >> 1, wc = w & 1, quad = l >> 4, li = l & 15;
#pragma unroll
  for (int i = 0; i < 4; i++) {
    int gn = m0 + wr * 64 + i * 16 + quad * 4;
#pragma unroll
    for (int j = 0; j < 4; j++) {
      int go = o0 + wc * 64 + j * 16 + li;
      float bias = pb[go];
      F4 xres; xres.v = *(const float4*)(x + ((size_t)b * 512 + go) * 1024 + gn);
      F4 o;
#pragma unroll
      for (int r = 0; r < 4; r++) o.f[r] = acc[i][j][r] + bias + xres.f[r];
      *(float4*)(out + ((size_t)b * 512 + go) * 1024 + gn) = o.v;
    }
  }
}

// ---------------------------------------------------------------------------
extern "C" void kernel_launch(void* const* d_in, const int* in_sizes, int n_in,
                              void* d_out, int out_size, void* d_ws, size_t ws_size,
                              hipStream_t stream) {
  const float* x  = (const float*)d_in[0];
  const float* nw = (const float*)d_in[1];
  const float* nb = (const float*)d_in[2];
  const float* qw = (const float*)d_in[3];
  const float* qb = (const float*)d_in[4];
  const float* pw = (const float*)d_in[5];
  const float* pb = (const float*)d_in[6];
  float* out = (float*)d_out;

  char* ws = (char*)d_ws;
  float2* stats = (float2*)ws;
  bf16* qwb = (bf16*)(ws + (64u << 10));
  bf16* pwb = (bf16*)(ws + (2u << 20));
  bf16* hnt = (bf16*)(ws + (4u << 20));   // reused as ont after qkv_gemm
  bf16* qsw = (bf16*)(ws + (20u << 20));
  bf16* ksw = (bf16*)(ws + (36u << 20));
  bf16* vsw = (bf16*)(ws + (52u << 20));
  bf16* ont = hnt;

  cvt_w<<<1024, 256, 0, stream>>>(qw, pw, qwb, pwb);
  gn_stats<<<512, 256, 0, stream>>>(x, stats);
  gn_apply<<<dim3(4, 16, 16), 256, 0, stream>>>(x, nw, nb, stats, hnt);
  qkv_gemm<<<dim3(12, 8, 16), 256, 0, stream>>>(hnt, qwb, qb, qsw, ksw, vsw);
  attn<<<dim3(128, 8, 1), 256, 0, stream>>>(qsw, ksw, vsw, ont);
  proj_gemm<<<dim3(4, 8, 16), 256, 0, stream>>>(ont, pwb, pb, x, out);
}